// Round 3
// baseline (8088.545 us; speedup 1.0000x reference)
//
#include <hip/hip_runtime.h>

#define NK 256
#define BB 128
#define CC 10
#define LL 16384
#define EPSV 1e-10f
#define G 16
#define XLSZ 6144

__device__ __forceinline__ int padidx(int a) { return a + (a >> 4); }

__device__ __forceinline__ void block_finish(int cnt, float mx,
                                             float* rm, int* rc,
                                             int Lout, float* out, int b, int k) {
    int tid = threadIdx.x;
    for (int off = 32; off; off >>= 1) {
        mx = fmaxf(mx, __shfl_down(mx, off));
        cnt += __shfl_down(cnt, off);
    }
    int wv = tid >> 6, ln = tid & 63;
    if (ln == 0) { rm[wv] = mx; rc[wv] = cnt; }
    __syncthreads();
    if (tid == 0) {
#pragma unroll
        for (int i = 1; i < 4; ++i) { mx = fmaxf(mx, rm[i]); cnt += rc[i]; }
        size_t o = (size_t)b * (2 * NK) + 2 * k;
        out[o] = (float)cnt / (float)Lout;
        out[o + 1] = mx;
    }
}

__global__ __launch_bounds__(256) void stats_kernel(const float* __restrict__ x,
                                                    float* __restrict__ wsf) {
    int row = blockIdx.x;
    const float4* x4 = (const float4*)(x + (size_t)row * LL);
    int tid = threadIdx.x;
    float s = 0.f, s2 = 0.f;
    for (int i = tid; i < LL / 4; i += 256) {
        float4 v = x4[i];
        s += v.x + v.y + v.z + v.w;
        s2 += v.x * v.x + v.y * v.y + v.z * v.z + v.w * v.w;
    }
    for (int off = 32; off; off >>= 1) {
        s += __shfl_down(s, off);
        s2 += __shfl_down(s2, off);
    }
    __shared__ float as_[4], as2_[4];
    int wv = tid >> 6, ln = tid & 63;
    if (ln == 0) { as_[wv] = s; as2_[wv] = s2; }
    __syncthreads();
    if (tid == 0) {
        float S = as_[0] + as_[1] + as_[2] + as_[3];
        float S2 = as2_[0] + as2_[1] + as2_[2] + as2_[3];
        float mean = S / (float)LL;
        float var = (S2 - (float)LL * mean * mean) / (float)(LL - 1);
        var = fmaxf(var, 0.f);
        float inv = 1.f / (sqrtf(var) + EPSV);
        wsf[row] = inv;
        wsf[1280 + row] = -mean * inv;
    }
}

__global__ __launch_bounds__(256) void prefix_kernel(const int* __restrict__ lengths,
                                                     const int* __restrict__ ncis,
                                                     int* __restrict__ wbase,
                                                     int* __restrict__ cbase) {
    __shared__ int s1[NK], s2[NK];
    int k = threadIdx.x;
    int v1 = lengths[k] * ncis[k];
    int v2 = ncis[k];
    s1[k] = v1; s2[k] = v2;
    for (int off = 1; off < NK; off <<= 1) {
        __syncthreads();
        int a = (k >= off) ? s1[k - off] : 0;
        int b = (k >= off) ? s2[k - off] : 0;
        __syncthreads();
        s1[k] += a; s2[k] += b;
    }
    __syncthreads();
    wbase[k] = s1[k] - v1;
    cbase[k] = s2[k] - v2;
}

// ================= small-d (d<=64): LDS decimated-transpose =================
template <int LEN>
__device__ __forceinline__ void conv_lds(
    const float* __restrict__ x, float* __restrict__ xl,
    const float* __restrict__ wsm, const int* __restrict__ choff,
    const float* __restrict__ cinv, const float* __restrict__ csh,
    float* rm, int* rc,
    int d, int ms, int Lout, int nci, float bias,
    float* __restrict__ out, int b, int k) {
    constexpr int W = G + LEN - 1;
    const int tid = threadIdx.x;

    int cnt = 0;
    float mx = -3.4e38f;
    float negb = -bias;

    int qpt = 256 / d;
    int MT = qpt * G;
    int MwU = MT + LEN - 1;
    int Mw = (MwU + 15) & ~15;
    if (((Mw >> 4) & 1) == 0) Mw += 16;  // keep padded write-stride odd
    int stotU = d * MwU;
    int Qmax = (Lout + d - 1) / d;
    int nit = d * qpt;
    bool active = tid < nit;
    int rho = 0, qi = 0;
    if (active) { rho = tid / qpt; qi = tid - rho * qpt; }
    int pb = padidx(rho * Mw + qi * G);  // base is mult of 16 -> linear+imm reads

    int rr0 = tid % d, mm0 = tid / d;
    int dr = 256 % d, dm = 256 / d;

    for (int qt = 0; qt < Qmax; qt += MT) {
        float acc[G];
#pragma unroll
        for (int g = 0; g < G; ++g) acc[g] = 0.f;
        int tb = (qt - ms) * d;
        int m0 = qt + qi * G - ms;
        bool interior = (m0 >= 0) && ((m0 + W) * d <= LL);

        for (int ci = 0; ci < nci; ++ci) {
            __syncthreads();
            const float* xc = x + choff[ci];
            float inv = cinv[ci], sh = csh[ci];
            {
                int rr = rr0, mm = mm0;
                for (int s = tid; s < stotU; s += 256) {
                    int t = tb + s;
                    if ((unsigned)t < (unsigned)LL)
                        xl[padidx(rr * Mw + mm)] = fmaf(xc[t], inv, sh);
                    rr += dr; mm += dm;
                    if (rr >= d) { rr -= d; ++mm; }
                }
            }
            __syncthreads();

            float wreg[LEN];
#pragma unroll
            for (int j = 0; j < LEN; ++j) wreg[j] = wsm[ci * LEN + j];

            if (interior) {
                float win[W];
#pragma unroll
                for (int i = 0; i < W; ++i) win[i] = xl[pb + i + (i >> 4)];
#pragma unroll
                for (int j = 0; j < LEN; ++j)
#pragma unroll
                    for (int g = 0; g < G; ++g)
                        acc[g] = fmaf(wreg[j], win[g + j], acc[g]);
            } else {
                float win[W];
#pragma unroll
                for (int i = 0; i < W; ++i) {
                    int u = rho + (m0 + i) * d;
                    float lv = xl[pb + i + (i >> 4)];
                    win[i] = ((unsigned)u < (unsigned)LL) ? lv : 0.f;
                }
#pragma unroll
                for (int j = 0; j < LEN; ++j)
#pragma unroll
                    for (int g = 0; g < G; ++g)
                        acc[g] = fmaf(wreg[j], win[g + j], acc[g]);
            }
        }

        if (active) {
            int qb = qt + qi * G;
            if ((qb + G) * d <= Lout) {
                float am = acc[0];
#pragma unroll
                for (int g = 1; g < G; ++g) am = fmaxf(am, acc[g]);
                mx = fmaxf(mx, am + bias);
#pragma unroll
                for (int g = 0; g < G; ++g) cnt += (acc[g] > negb) ? 1 : 0;
            } else {
#pragma unroll
                for (int g = 0; g < G; ++g) {
                    int t = (qb + g) * d + rho;
                    if (t < Lout) {
                        float y = acc[g] + bias;
                        cnt += (y > 0.f) ? 1 : 0;
                        mx = fmaxf(mx, y);
                    }
                }
            }
        }
    }
    block_finish(cnt, mx, rm, rc, Lout, out, b, k);
}

__global__ __launch_bounds__(256) void conv_small(
    const float* __restrict__ x, const float* __restrict__ weights,
    const float* __restrict__ biases,
    const int* __restrict__ lengths, const int* __restrict__ dil,
    const int* __restrict__ pad, const int* __restrict__ ncis,
    const int* __restrict__ chidx,
    const float* __restrict__ wsf, const int* __restrict__ wbase,
    const int* __restrict__ cbase, float* __restrict__ out) {
    int k = blockIdx.x, b = blockIdx.y;
    int d = dil[k];
    if (d > 64) return;
    __shared__ float xl[XLSZ];
    __shared__ float wsm[CC * 11];
    __shared__ int choff[CC];
    __shared__ float cinv[CC], csh[CC];
    __shared__ float rm[4];
    __shared__ int rc[4];

    int tid = threadIdx.x;
    int len = lengths[k], p = pad[k], nci = ncis[k];
    int wb = wbase[k], cb = cbase[k];

    if (tid < nci) {
        int ch = chidx[cb + tid];
        choff[tid] = (b * CC + ch) * LL;
        cinv[tid] = wsf[b * CC + ch];
        csh[tid] = wsf[1280 + b * CC + ch];
    }
    int nw = nci * len;
    for (int i = tid; i < nw; i += 256) wsm[i] = weights[wb + i];
    __syncthreads();

    int span = (len - 1) * d;
    int Lout = LL + 2 * p - span;
    int ms = p / d;
    float bias = biases[k];

    switch (len) {
        case 7:
            conv_lds<7>(x, xl, wsm, choff, cinv, csh, rm, rc, d, ms, Lout, nci, bias, out, b, k);
            break;
        case 9:
            conv_lds<9>(x, xl, wsm, choff, cinv, csh, rm, rc, d, ms, Lout, nci, bias, out, b, k);
            break;
        default:
            conv_lds<11>(x, xl, wsm, choff, cinv, csh, rm, rc, d, ms, Lout, nci, bias, out, b, k);
            break;
    }
}

// ================= large-d (d>64): direct global windows =================
template <int LEN>
__device__ __forceinline__ void conv_run16(
    const float* __restrict__ x,
    const float* __restrict__ wsmR, const float* __restrict__ wsmS,
    const int* __restrict__ choff, const float* __restrict__ cinv,
    const float* __restrict__ csh,
    float* rm, int* rc,
    int d, int ms, int Lout, int nci, float bias, float csum,
    float* __restrict__ out, int b, int k) {
    constexpr int W = G + LEN - 1;
    const int tid = threadIdx.x;
    int cnt = 0;
    float mx = -3.4e38f;
    float selI = csum + bias, selE = bias;
    float negI = -selI, negE = -selE;

    int Qmax = (Lout + d - 1) / d;
    int NB = (Qmax + G - 1) / G;
    int ntot = d * NB;

    for (int n0 = 0; n0 < ntot; n0 += 256) {
        int n = n0 + tid;
        bool active = n < ntot;
        int nn = active ? n : 0;
        int rho = nn % d;
        int qb = (nn / d) * G;
        int m0 = qb - ms;
        bool interior = (m0 >= 0) && ((m0 + W) * d <= LL);

        float acc[G];
#pragma unroll
        for (int g = 0; g < G; ++g) acc[g] = 0.f;

        if (interior) {
            for (int ci = 0; ci < nci; ++ci) {
                const float* xp = x + choff[ci] + rho + m0 * d;
                float wreg[LEN];
#pragma unroll
                for (int j = 0; j < LEN; ++j) wreg[j] = wsmS[ci * LEN + j];
                float win[W];
#pragma unroll
                for (int i = 0; i < W; ++i) win[i] = xp[i * d];
#pragma unroll
                for (int j = 0; j < LEN; ++j)
#pragma unroll
                    for (int g = 0; g < G; ++g)
                        acc[g] = fmaf(wreg[j], win[g + j], acc[g]);
            }
        } else {
            for (int ci = 0; ci < nci; ++ci) {
                const float* xc = x + choff[ci];
                float inv = cinv[ci], sh = csh[ci];
                float wreg[LEN];
#pragma unroll
                for (int j = 0; j < LEN; ++j) wreg[j] = wsmR[ci * LEN + j];
                float win[W];
#pragma unroll
                for (int i = 0; i < W; ++i) {
                    int u = rho + (m0 + i) * d;
                    bool v = (unsigned)u < (unsigned)LL;
                    float xv = xc[v ? u : 0];
                    win[i] = v ? fmaf(xv, inv, sh) : 0.f;
                }
#pragma unroll
                for (int j = 0; j < LEN; ++j)
#pragma unroll
                    for (int g = 0; g < G; ++g)
                        acc[g] = fmaf(wreg[j], win[g + j], acc[g]);
            }
        }

        if (active) {
            float sel = interior ? selI : selE;
            float neg = interior ? negI : negE;
            if ((qb + G) * d <= Lout) {
                float am = acc[0];
#pragma unroll
                for (int g = 1; g < G; ++g) am = fmaxf(am, acc[g]);
                mx = fmaxf(mx, am + sel);
#pragma unroll
                for (int g = 0; g < G; ++g) cnt += (acc[g] > neg) ? 1 : 0;
            } else {
#pragma unroll
                for (int g = 0; g < G; ++g) {
                    int t = (qb + g) * d + rho;
                    if (t < Lout) {
                        float y = acc[g] + sel;
                        cnt += (y > 0.f) ? 1 : 0;
                        mx = fmaxf(mx, y);
                    }
                }
            }
        }
    }
    block_finish(cnt, mx, rm, rc, Lout, out, b, k);
}

template <int LEN>
__device__ __forceinline__ void conv_run4(
    const float* __restrict__ x,
    const float* __restrict__ wsmR,
    const int* __restrict__ choff, const float* __restrict__ cinv,
    const float* __restrict__ csh,
    float* rm, int* rc,
    int d, int ms, int Lout, int nci, float bias,
    float* __restrict__ out, int b, int k) {
    constexpr int G4 = 4;
    constexpr int W = G4 + LEN - 1;
    const int tid = threadIdx.x;
    int cnt = 0;
    float mx = -3.4e38f;

    int Qmax = (Lout + d - 1) / d;
    int NB = (Qmax + G4 - 1) / G4;
    int ntot = d * NB;

    for (int n0 = 0; n0 < ntot; n0 += 256) {
        int n = n0 + tid;
        bool active = n < ntot;
        int nn = active ? n : 0;
        int rho = nn % d;
        int qb = (nn / d) * G4;
        int m0 = qb - ms;

        float acc[G4];
#pragma unroll
        for (int g = 0; g < G4; ++g) acc[g] = 0.f;

        for (int ci = 0; ci < nci; ++ci) {
            const float* xc = x + choff[ci];
            float inv = cinv[ci], sh = csh[ci];
            float wreg[LEN];
#pragma unroll
            for (int j = 0; j < LEN; ++j) wreg[j] = wsmR[ci * LEN + j];
            float win[W];
#pragma unroll
            for (int i = 0; i < W; ++i) {
                int u = rho + (m0 + i) * d;
                bool v = (unsigned)u < (unsigned)LL;
                float xv = xc[v ? u : 0];
                win[i] = v ? fmaf(xv, inv, sh) : 0.f;
            }
#pragma unroll
            for (int j = 0; j < LEN; ++j)
#pragma unroll
                for (int g = 0; g < G4; ++g)
                    acc[g] = fmaf(wreg[j], win[g + j], acc[g]);
        }

        if (active) {
#pragma unroll
            for (int g = 0; g < G4; ++g) {
                int t = (qb + g) * d + rho;
                if (t < Lout) {
                    float y = acc[g] + bias;
                    cnt += (y > 0.f) ? 1 : 0;
                    mx = fmaxf(mx, y);
                }
            }
        }
    }
    block_finish(cnt, mx, rm, rc, Lout, out, b, k);
}

__global__ __launch_bounds__(256) void conv_big(
    const float* __restrict__ x, const float* __restrict__ weights,
    const float* __restrict__ biases,
    const int* __restrict__ lengths, const int* __restrict__ dil,
    const int* __restrict__ pad, const int* __restrict__ ncis,
    const int* __restrict__ chidx,
    const float* __restrict__ wsf, const int* __restrict__ wbase,
    const int* __restrict__ cbase, float* __restrict__ out) {
    int k = blockIdx.x, b = blockIdx.y;
    int d = dil[k];
    if (d <= 64) return;
    __shared__ float wsmR[CC * 11], wsmS[CC * 11];
    __shared__ int choff[CC];
    __shared__ float cinv[CC], csh[CC];
    __shared__ float rm[4];
    __shared__ int rc[4];

    int tid = threadIdx.x;
    int len = lengths[k], p = pad[k], nci = ncis[k];
    int wb = wbase[k], cb = cbase[k];

    if (tid < nci) {
        int ch = chidx[cb + tid];
        choff[tid] = (b * CC + ch) * LL;
        cinv[tid] = wsf[b * CC + ch];
        csh[tid] = wsf[1280 + b * CC + ch];
    }
    __syncthreads();
    int nw = nci * len;
    for (int i = tid; i < nw; i += 256) {
        float w = weights[wb + i];
        wsmR[i] = w;
        wsmS[i] = w * cinv[i / len];
    }
    __syncthreads();

    float csum = 0.f;
    for (int ci = 0; ci < nci; ++ci) {
        float s = 0.f;
        for (int j = 0; j < len; ++j) s += wsmR[ci * len + j];
        csum += csh[ci] * s;
    }

    int span = (len - 1) * d;
    int Lout = LL + 2 * p - span;
    int ms = p / d;
    float bias = biases[k];
    int Qmax = (Lout + d - 1) / d;

    if (Qmax <= 16) {
        switch (len) {
            case 7:
                conv_run4<7>(x, wsmR, choff, cinv, csh, rm, rc, d, ms, Lout, nci, bias, out, b, k);
                break;
            case 9:
                conv_run4<9>(x, wsmR, choff, cinv, csh, rm, rc, d, ms, Lout, nci, bias, out, b, k);
                break;
            default:
                conv_run4<11>(x, wsmR, choff, cinv, csh, rm, rc, d, ms, Lout, nci, bias, out, b, k);
                break;
        }
    } else {
        switch (len) {
            case 7:
                conv_run16<7>(x, wsmR, wsmS, choff, cinv, csh, rm, rc, d, ms, Lout, nci, bias, csum, out, b, k);
                break;
            case 9:
                conv_run16<9>(x, wsmR, wsmS, choff, cinv, csh, rm, rc, d, ms, Lout, nci, bias, csum, out, b, k);
                break;
            default:
                conv_run16<11>(x, wsmR, wsmS, choff, cinv, csh, rm, rc, d, ms, Lout, nci, bias, csum, out, b, k);
                break;
        }
    }
}

extern "C" void kernel_launch(void* const* d_in, const int* in_sizes, int n_in,
                              void* d_out, int out_size, void* d_ws, size_t ws_size,
                              hipStream_t stream) {
    const float* x = (const float*)d_in[0];
    const float* weights = (const float*)d_in[1];
    const float* biases = (const float*)d_in[2];
    const int* lengths = (const int*)d_in[3];
    const int* dil = (const int*)d_in[4];
    const int* pad = (const int*)d_in[5];
    const int* ncis = (const int*)d_in[6];
    const int* chidx = (const int*)d_in[7];
    float* out = (float*)d_out;

    float* wsf = (float*)d_ws;
    int* wbase = (int*)((char*)d_ws + 2560 * sizeof(float));
    int* cbase = wbase + NK;

    stats_kernel<<<dim3(BB * CC), dim3(256), 0, stream>>>(x, wsf);
    prefix_kernel<<<dim3(1), dim3(256), 0, stream>>>(lengths, ncis, wbase, cbase);
    dim3 grid(NK, BB);
    conv_small<<<grid, dim3(256), 0, stream>>>(x, weights, biases, lengths, dil,
                                               pad, ncis, chidx, wsf, wbase,
                                               cbase, out);
    conv_big<<<grid, dim3(256), 0, stream>>>(x, weights, biases, lengths, dil,
                                             pad, ncis, chidx, wsf, wbase,
                                             cbase, out);
}

// Round 5
// 5886.494 us; speedup vs baseline: 1.3741x; 1.3741x over previous
//
#include <hip/hip_runtime.h>

#define NK 256
#define BB 128
#define CC 10
#define LL 16384
#define EPSV 1e-10f
#define G 16
// worst case: conv_S qpt=3 (d in [65,85]), padidx(84*80+57) = 7200 floats
#define XLSZ 7424

__device__ __forceinline__ int padidx(int a) { return a + (a >> 4); }

__device__ __forceinline__ void block_finish(int cnt, float mx,
                                             float* rm, int* rc,
                                             int Lout, float* out, int b, int k) {
    int tid = threadIdx.x;
    for (int off = 32; off; off >>= 1) {
        mx = fmaxf(mx, __shfl_down(mx, off));
        cnt += __shfl_down(cnt, off);
    }
    int wv = tid >> 6, ln = tid & 63;
    if (ln == 0) { rm[wv] = mx; rc[wv] = cnt; }
    __syncthreads();
    if (tid == 0) {
#pragma unroll
        for (int i = 1; i < 4; ++i) { mx = fmaxf(mx, rm[i]); cnt += rc[i]; }
        size_t o = (size_t)b * (2 * NK) + 2 * k;
        out[o] = (float)cnt / (float)Lout;
        out[o + 1] = mx;
    }
}

__global__ __launch_bounds__(256) void stats_kernel(const float* __restrict__ x,
                                                    float* __restrict__ wsf) {
    int row = blockIdx.x;
    const float4* x4 = (const float4*)(x + (size_t)row * LL);
    int tid = threadIdx.x;
    float s = 0.f, s2 = 0.f;
    for (int i = tid; i < LL / 4; i += 256) {
        float4 v = x4[i];
        s += v.x + v.y + v.z + v.w;
        s2 += v.x * v.x + v.y * v.y + v.z * v.z + v.w * v.w;
    }
    for (int off = 32; off; off >>= 1) {
        s += __shfl_down(s, off);
        s2 += __shfl_down(s2, off);
    }
    __shared__ float as_[4], as2_[4];
    int wv = tid >> 6, ln = tid & 63;
    if (ln == 0) { as_[wv] = s; as2_[wv] = s2; }
    __syncthreads();
    if (tid == 0) {
        float S = as_[0] + as_[1] + as_[2] + as_[3];
        float S2 = as2_[0] + as2_[1] + as2_[2] + as2_[3];
        float mean = S / (float)LL;
        float var = (S2 - (float)LL * mean * mean) / (float)(LL - 1);
        var = fmaxf(var, 0.f);
        float inv = 1.f / (sqrtf(var) + EPSV);
        wsf[row] = inv;
        wsf[1280 + row] = -mean * inv;
    }
}

__global__ __launch_bounds__(256) void prefix_kernel(const int* __restrict__ lengths,
                                                     const int* __restrict__ ncis,
                                                     int* __restrict__ wbase,
                                                     int* __restrict__ cbase) {
    __shared__ int s1[NK], s2[NK];
    int k = threadIdx.x;
    int v1 = lengths[k] * ncis[k];
    int v2 = ncis[k];
    s1[k] = v1; s2[k] = v2;
    for (int off = 1; off < NK; off <<= 1) {
        __syncthreads();
        int a = (k >= off) ? s1[k - off] : 0;
        int b = (k >= off) ? s2[k - off] : 0;
        __syncthreads();
        s1[k] += a; s2[k] += b;
    }
    __syncthreads();
    wbase[k] = s1[k] - v1;
    cbase[k] = s2[k] - v2;
}

// ============== S: d < 128, decimated-transpose LDS (padded layout) ==========
template <int LEN>
__device__ __forceinline__ void conv_S(
    const float* __restrict__ x, float* __restrict__ xl,
    const float* __restrict__ wsm, const int* __restrict__ choff,
    const float* __restrict__ cinv, const float* __restrict__ csh,
    float* rm, int* rc, int d, int ms, int Lout, int nci, float bias,
    float* __restrict__ out, int b, int k) {
    constexpr int W = G + LEN - 1;
    const int tid = threadIdx.x;
    int cnt = 0;
    float mx = -3.4e38f;
    float negb = -bias;

    int qpt = 256 / d;
    int MT = qpt * G;
    int MwU = MT + LEN - 1;
    int Mw = (MwU + 15) & ~15;
    if (((Mw >> 4) & 1) == 0) Mw += 16;  // padded write-stride odd
    int stotU = d * MwU;
    int Qmax = (Lout + d - 1) / d;
    int nit = d * qpt;
    bool active = tid < nit;
    int rho = 0, qi = 0;
    if (active) { rho = tid / qpt; qi = tid - rho * qpt; }
    int pb = padidx(rho * Mw + qi * G);

    int rr0 = tid % d, mm0 = tid / d;
    int dr = 256 % d, dm = 256 / d;

    for (int qt = 0; qt < Qmax; qt += MT) {
        float acc[G];
#pragma unroll
        for (int g = 0; g < G; ++g) acc[g] = 0.f;
        int tb = (qt - ms) * d;

        for (int ci = 0; ci < nci; ++ci) {
            __syncthreads();
            const float* xc = x + choff[ci];
            float inv = cinv[ci], sh = csh[ci];
            int rr = rr0, mm = mm0;
            for (int s = tid; s < stotU; s += 256) {
                int t = tb + s;
                float v = 0.f;
                if ((unsigned)t < (unsigned)LL) v = fmaf(xc[t], inv, sh);
                xl[padidx(rr * Mw + mm)] = v;
                rr += dr; mm += dm;
                if (rr >= d) { rr -= d; ++mm; }
            }
            __syncthreads();

            float wreg[LEN];
#pragma unroll
            for (int j = 0; j < LEN; ++j) wreg[j] = wsm[ci * LEN + j];
            float win[W];
#pragma unroll
            for (int i = 0; i < W; ++i) win[i] = xl[pb + i + (i >> 4)];
#pragma unroll
            for (int j = 0; j < LEN; ++j)
#pragma unroll
                for (int g = 0; g < G; ++g)
                    acc[g] = fmaf(wreg[j], win[g + j], acc[g]);
        }

        if (active) {
            int qb = qt + qi * G;
            if ((qb + G) * d <= Lout) {
                float am = acc[0];
#pragma unroll
                for (int g = 1; g < G; ++g) am = fmaxf(am, acc[g]);
                mx = fmaxf(mx, am + bias);
#pragma unroll
                for (int g = 0; g < G; ++g) cnt += (acc[g] > negb) ? 1 : 0;
            } else {
#pragma unroll
                for (int g = 0; g < G; ++g) {
                    int t = (qb + g) * d + rho;
                    if (t < Lout) {
                        float y = acc[g] + bias;
                        cnt += (y > 0.f) ? 1 : 0;
                        mx = fmaxf(mx, y);
                    }
                }
            }
        }
    }
    block_finish(cnt, mx, rm, rc, Lout, out, b, k);
}

// ============== T1: 128 <= d <= 256, linear [m][rho] LDS =====================
template <int LEN>
__device__ __forceinline__ void conv_T1(
    const float* __restrict__ x, float* __restrict__ xl,
    const float* __restrict__ wsm, const int* __restrict__ choff,
    const float* __restrict__ cinv, const float* __restrict__ csh,
    float* rm, int* rc, int d, int ms, int Lout, int nci, float bias,
    float* __restrict__ out, int b, int k) {
    constexpr int W = G + LEN - 1;
    const int tid = threadIdx.x;
    int cnt = 0;
    float mx = -3.4e38f;
    float negb = -bias;

    int qpt = 256 / d;           // 1 or 2
    int qi = tid / d;
    int rho = tid - qi * d;
    bool active = qi < qpt;
    int MwT = qpt * G + LEN - 1;
    int stot = d * MwT;
    int MT = qpt * G;
    int Qmax = (Lout + d - 1) / d;
    int rbase = active ? (qi * G * d + rho) : 0;

    for (int qt = 0; qt < Qmax; qt += MT) {
        float acc[G];
#pragma unroll
        for (int g = 0; g < G; ++g) acc[g] = 0.f;
        int tb = (qt - ms) * d;

        for (int ci = 0; ci < nci; ++ci) {
            __syncthreads();
            const float* xc = x + choff[ci];
            float inv = cinv[ci], sh = csh[ci];
            for (int s = tid; s < stot; s += 256) {
                int t = tb + s;
                float v = 0.f;
                if ((unsigned)t < (unsigned)LL) v = fmaf(xc[t], inv, sh);
                xl[s] = v;
            }
            __syncthreads();

            float wreg[LEN];
#pragma unroll
            for (int j = 0; j < LEN; ++j) wreg[j] = wsm[ci * LEN + j];
            float win[W];
#pragma unroll
            for (int i = 0; i < W; ++i) win[i] = xl[rbase + i * d];
#pragma unroll
            for (int j = 0; j < LEN; ++j)
#pragma unroll
                for (int g = 0; g < G; ++g)
                    acc[g] = fmaf(wreg[j], win[g + j], acc[g]);
        }

        if (active) {
            int qb = qt + qi * G;
            if ((qb + G) * d <= Lout) {
                float am = acc[0];
#pragma unroll
                for (int g = 1; g < G; ++g) am = fmaxf(am, acc[g]);
                mx = fmaxf(mx, am + bias);
#pragma unroll
                for (int g = 0; g < G; ++g) cnt += (acc[g] > negb) ? 1 : 0;
            } else {
#pragma unroll
                for (int g = 0; g < G; ++g) {
                    int t = (qb + g) * d + rho;
                    if (t < Lout) {
                        float y = acc[g] + bias;
                        cnt += (y > 0.f) ? 1 : 0;
                        mx = fmaxf(mx, y);
                    }
                }
            }
        }
    }
    block_finish(cnt, mx, rm, rc, Lout, out, b, k);
}

// ============== T2: d > 256, rho-blocked [M][256] LDS, imm-offset reads ======
template <int LEN, int GG>
__device__ __forceinline__ void conv_T2(
    const float* __restrict__ x, float* __restrict__ xl,
    const float* __restrict__ wsm, const int* __restrict__ choff,
    const float* __restrict__ cinv, const float* __restrict__ csh,
    float* rm, int* rc, int d, int ms, int Lout, int nci, float bias,
    float* __restrict__ out, int b, int k) {
    constexpr int M = GG + LEN - 1;
    const int tid = threadIdx.x;
    int cnt = 0;
    float mx = -3.4e38f;
    int Qmax = (Lout + d - 1) / d;

    for (int r0 = 0; r0 < d; r0 += 256) {
        int rho = r0 + tid;
        bool active = rho < d;
        for (int qt = 0; qt < Qmax; qt += GG) {
            float acc[GG];
#pragma unroll
            for (int g = 0; g < GG; ++g) acc[g] = 0.f;
            int m0 = qt - ms;

            for (int ci = 0; ci < nci; ++ci) {
                __syncthreads();
                const float* xc = x + choff[ci];
                float inv = cinv[ci], sh = csh[ci];
                int tbase = m0 * d + r0 + tid;
#pragma unroll
                for (int mm = 0; mm < M; ++mm) {
                    int t = tbase + mm * d;
                    float v = 0.f;
                    if ((unsigned)t < (unsigned)LL) v = fmaf(xc[t], inv, sh);
                    xl[mm * 256 + tid] = v;
                }
                __syncthreads();

                float wreg[LEN];
#pragma unroll
                for (int j = 0; j < LEN; ++j) wreg[j] = wsm[ci * LEN + j];
                float win[M];
#pragma unroll
                for (int mm = 0; mm < M; ++mm) win[mm] = xl[mm * 256 + tid];
#pragma unroll
                for (int j = 0; j < LEN; ++j)
#pragma unroll
                    for (int g = 0; g < GG; ++g)
                        acc[g] = fmaf(wreg[j], win[g + j], acc[g]);
            }

            if (active) {
#pragma unroll
                for (int g = 0; g < GG; ++g) {
                    int t = (qt + g) * d + rho;
                    if (t < Lout) {
                        float y = acc[g] + bias;
                        cnt += (y > 0.f) ? 1 : 0;
                        mx = fmaxf(mx, y);
                    }
                }
            }
        }
    }
    block_finish(cnt, mx, rm, rc, Lout, out, b, k);
}

__global__ __launch_bounds__(256) void conv_kernel(
    const float* __restrict__ x, const float* __restrict__ weights,
    const float* __restrict__ biases,
    const int* __restrict__ lengths, const int* __restrict__ dil,
    const int* __restrict__ pad, const int* __restrict__ ncis,
    const int* __restrict__ chidx,
    const float* __restrict__ wsf, const int* __restrict__ wbase,
    const int* __restrict__ cbase, float* __restrict__ out) {
    int k = blockIdx.x, b = blockIdx.y;
    __shared__ float xl[XLSZ];
    __shared__ float wsm[CC * 11];
    __shared__ int choff[CC];
    __shared__ float cinv[CC], csh[CC];
    __shared__ float rm[4];
    __shared__ int rc[4];

    int tid = threadIdx.x;
    int len = lengths[k], d = dil[k], p = pad[k], nci = ncis[k];
    int wb = wbase[k], cb = cbase[k];

    if (tid < nci) {
        int ch = chidx[cb + tid];
        choff[tid] = (b * CC + ch) * LL;
        cinv[tid] = wsf[b * CC + ch];
        csh[tid] = wsf[1280 + b * CC + ch];
    }
    int nw = nci * len;
    for (int i = tid; i < nw; i += 256) wsm[i] = weights[wb + i];
    __syncthreads();

    int span = (len - 1) * d;
    int Lout = LL + 2 * p - span;
    int ms = p / d;
    float bias = biases[k];
    int Qmax = (Lout + d - 1) / d;

    if (d < 128) {
        switch (len) {
            case 7:  conv_S<7>(x, xl, wsm, choff, cinv, csh, rm, rc, d, ms, Lout, nci, bias, out, b, k); break;
            case 9:  conv_S<9>(x, xl, wsm, choff, cinv, csh, rm, rc, d, ms, Lout, nci, bias, out, b, k); break;
            default: conv_S<11>(x, xl, wsm, choff, cinv, csh, rm, rc, d, ms, Lout, nci, bias, out, b, k); break;
        }
    } else if (d <= 256) {
        switch (len) {
            case 7:  conv_T1<7>(x, xl, wsm, choff, cinv, csh, rm, rc, d, ms, Lout, nci, bias, out, b, k); break;
            case 9:  conv_T1<9>(x, xl, wsm, choff, cinv, csh, rm, rc, d, ms, Lout, nci, bias, out, b, k); break;
            default: conv_T1<11>(x, xl, wsm, choff, cinv, csh, rm, rc, d, ms, Lout, nci, bias, out, b, k); break;
        }
    } else if (Qmax > 12) {
        switch (len) {
            case 7:  conv_T2<7, 16>(x, xl, wsm, choff, cinv, csh, rm, rc, d, ms, Lout, nci, bias, out, b, k); break;
            case 9:  conv_T2<9, 16>(x, xl, wsm, choff, cinv, csh, rm, rc, d, ms, Lout, nci, bias, out, b, k); break;
            default: conv_T2<11, 16>(x, xl, wsm, choff, cinv, csh, rm, rc, d, ms, Lout, nci, bias, out, b, k); break;
        }
    } else {
        switch (len) {
            case 7:  conv_T2<7, 4>(x, xl, wsm, choff, cinv, csh, rm, rc, d, ms, Lout, nci, bias, out, b, k); break;
            case 9:  conv_T2<9, 4>(x, xl, wsm, choff, cinv, csh, rm, rc, d, ms, Lout, nci, bias, out, b, k); break;
            default: conv_T2<11, 4>(x, xl, wsm, choff, cinv, csh, rm, rc, d, ms, Lout, nci, bias, out, b, k); break;
        }
    }
}

extern "C" void kernel_launch(void* const* d_in, const int* in_sizes, int n_in,
                              void* d_out, int out_size, void* d_ws, size_t ws_size,
                              hipStream_t stream) {
    const float* x = (const float*)d_in[0];
    const float* weights = (const float*)d_in[1];
    const float* biases = (const float*)d_in[2];
    const int* lengths = (const int*)d_in[3];
    const int* dil = (const int*)d_in[4];
    const int* pad = (const int*)d_in[5];
    const int* ncis = (const int*)d_in[6];
    const int* chidx = (const int*)d_in[7];
    float* out = (float*)d_out;

    float* wsf = (float*)d_ws;
    int* wbase = (int*)((char*)d_ws + 2560 * sizeof(float));
    int* cbase = wbase + NK;

    stats_kernel<<<dim3(BB * CC), dim3(256), 0, stream>>>(x, wsf);
    prefix_kernel<<<dim3(1), dim3(256), 0, stream>>>(lengths, ncis, wbase, cbase);
    dim3 grid(NK, BB);
    conv_kernel<<<grid, dim3(256), 0, stream>>>(x, weights, biases, lengths, dil,
                                                pad, ncis, chidx, wsf, wbase,
                                                cbase, out);
}

// Round 6
// 4507.204 us; speedup vs baseline: 1.7946x; 1.3060x over previous
//
#include <hip/hip_runtime.h>

#define NK 256
#define BB 128
#define CC 10
#define LL 16384
#define EPSV 1e-10f
#define G 16
// max staged: d=256,qpt=1: stot=256*26=6656 -> g(6655)=6862
#define XLSZ 7424

__device__ __forceinline__ int gidx(int a) { return a + (a >> 5); }

__device__ __forceinline__ void block_finish(int cnt, float mx,
                                             float* rm, int* rc,
                                             int Lout, float* out, int b, int k) {
    int tid = threadIdx.x;
    for (int off = 32; off; off >>= 1) {
        mx = fmaxf(mx, __shfl_down(mx, off));
        cnt += __shfl_down(cnt, off);
    }
    int wv = tid >> 6, ln = tid & 63;
    if (ln == 0) { rm[wv] = mx; rc[wv] = cnt; }
    __syncthreads();
    if (tid == 0) {
#pragma unroll
        for (int i = 1; i < 4; ++i) { mx = fmaxf(mx, rm[i]); cnt += rc[i]; }
        size_t o = (size_t)b * (2 * NK) + 2 * k;
        out[o] = (float)cnt / (float)Lout;
        out[o + 1] = mx;
    }
}

__global__ __launch_bounds__(256) void stats_kernel(const float* __restrict__ x,
                                                    float* __restrict__ wsf) {
    int row = blockIdx.x;
    const float4* x4 = (const float4*)(x + (size_t)row * LL);
    int tid = threadIdx.x;
    float s = 0.f, s2 = 0.f;
    for (int i = tid; i < LL / 4; i += 256) {
        float4 v = x4[i];
        s += v.x + v.y + v.z + v.w;
        s2 += v.x * v.x + v.y * v.y + v.z * v.z + v.w * v.w;
    }
    for (int off = 32; off; off >>= 1) {
        s += __shfl_down(s, off);
        s2 += __shfl_down(s2, off);
    }
    __shared__ float as_[4], as2_[4];
    int wv = tid >> 6, ln = tid & 63;
    if (ln == 0) { as_[wv] = s; as2_[wv] = s2; }
    __syncthreads();
    if (tid == 0) {
        float S = as_[0] + as_[1] + as_[2] + as_[3];
        float S2 = as2_[0] + as2_[1] + as2_[2] + as2_[3];
        float mean = S / (float)LL;
        float var = (S2 - (float)LL * mean * mean) / (float)(LL - 1);
        var = fmaxf(var, 0.f);
        float inv = 1.f / (sqrtf(var) + EPSV);
        wsf[row] = inv;
        wsf[1280 + row] = -mean * inv;
    }
}

__global__ __launch_bounds__(256) void prefix_kernel(const int* __restrict__ lengths,
                                                     const int* __restrict__ ncis,
                                                     int* __restrict__ wbase,
                                                     int* __restrict__ cbase) {
    __shared__ int s1[NK], s2[NK];
    int k = threadIdx.x;
    int v1 = lengths[k] * ncis[k];
    int v2 = ncis[k];
    s1[k] = v1; s2[k] = v2;
    for (int off = 1; off < NK; off <<= 1) {
        __syncthreads();
        int a = (k >= off) ? s1[k - off] : 0;
        int b = (k >= off) ? s2[k - off] : 0;
        __syncthreads();
        s1[k] += a; s2[k] += b;
    }
    __syncthreads();
    wbase[k] = s1[k] - v1;
    cbase[k] = s2[k] - v2;
}

// ======== S2: d <= 256 — linear-t LDS tile, gap-padded strided reads ========
template <int LEN>
__device__ __forceinline__ void conv_S2(
    const float* __restrict__ x, float* __restrict__ xl,
    const float* __restrict__ wsm, const int* __restrict__ choff,
    const float* __restrict__ cinv, const float* __restrict__ csh,
    float* rm, int* rc, int d, int ms, int Lout, int nci, float bias,
    float* __restrict__ out, int b, int k) {
    constexpr int W = G + LEN - 1;
    const int tid = threadIdx.x;
    int cnt = 0;
    float mx = -3.4e38f;
    float negb = -bias;

    int qpt = 256 / d;
    int MT = qpt * G;
    int stot = d * (MT + LEN - 1);
    int Qmax = (Lout + d - 1) / d;
    int qi = tid / d;
    int rho = tid - qi * d;
    bool active = qi < qpt;
    int a0 = active ? (qi * G * d + rho) : 0;
    int sl0 = gidx(tid);

    for (int qt = 0; qt < Qmax; qt += MT) {
        float acc[G];
#pragma unroll
        for (int g = 0; g < G; ++g) acc[g] = 0.f;
        int tb = (qt - ms) * d;
        bool tileInt = (tb >= 0) && (tb + stot <= LL);

        for (int ci = 0; ci < nci; ++ci) {
            __syncthreads();
            const float* xc = x + choff[ci];
            float inv = cinv[ci], sh = csh[ci];
            if (tileInt) {
                const float* xp = xc + tb;
                int sl = sl0;
                for (int s = tid; s < stot; s += 256) {
                    xl[sl] = fmaf(xp[s], inv, sh);
                    sl += 264;
                }
            } else {
                int sl = sl0;
                for (int s = tid; s < stot; s += 256) {
                    int t = tb + s;
                    float v = 0.f;
                    if ((unsigned)t < (unsigned)LL) v = fmaf(xc[t], inv, sh);
                    xl[sl] = v;
                    sl += 264;
                }
            }
            __syncthreads();

            float wreg[LEN];
#pragma unroll
            for (int j = 0; j < LEN; ++j) wreg[j] = wsm[ci * LEN + j];
            float win[W];
            int a = a0;
#pragma unroll
            for (int i = 0; i < W; ++i) {
                win[i] = xl[gidx(a)];
                a += d;
            }
#pragma unroll
            for (int j = 0; j < LEN; ++j)
#pragma unroll
                for (int g = 0; g < G; ++g)
                    acc[g] = fmaf(wreg[j], win[g + j], acc[g]);
        }

        if (active) {
            int qb = qt + qi * G;
            if ((qb + G) * d <= Lout) {
                float am = acc[0];
#pragma unroll
                for (int g = 1; g < G; ++g) am = fmaxf(am, acc[g]);
                mx = fmaxf(mx, am + bias);
#pragma unroll
                for (int g = 0; g < G; ++g) cnt += (acc[g] > negb) ? 1 : 0;
            } else {
#pragma unroll
                for (int g = 0; g < G; ++g) {
                    int t = (qb + g) * d + rho;
                    if (t < Lout) {
                        float y = acc[g] + bias;
                        cnt += (y > 0.f) ? 1 : 0;
                        mx = fmaxf(mx, y);
                    }
                }
            }
        }
    }
    block_finish(cnt, mx, rm, rc, Lout, out, b, k);
}

// ======== T2: d > 256 — rho-blocked [M][256] LDS, imm-offset reads ==========
template <int LEN, int GG>
__device__ __forceinline__ void conv_T2(
    const float* __restrict__ x, float* __restrict__ xl,
    const float* __restrict__ wsm, const int* __restrict__ choff,
    const float* __restrict__ cinv, const float* __restrict__ csh,
    float* rm, int* rc, int d, int ms, int Lout, int nci, float bias,
    float* __restrict__ out, int b, int k) {
    constexpr int M = GG + LEN - 1;
    const int tid = threadIdx.x;
    int cnt = 0;
    float mx = -3.4e38f;
    int Qmax = (Lout + d - 1) / d;

    for (int r0 = 0; r0 < d; r0 += 256) {
        int rho = r0 + tid;
        bool active = rho < d;
        for (int qt = 0; qt < Qmax; qt += GG) {
            float acc[GG];
#pragma unroll
            for (int g = 0; g < GG; ++g) acc[g] = 0.f;
            int m0 = qt - ms;
            int tlo = m0 * d + r0;
            bool tileInt = (tlo >= 0) && (tlo + 255 + (M - 1) * d < LL);

            for (int ci = 0; ci < nci; ++ci) {
                __syncthreads();
                const float* xc = x + choff[ci];
                float inv = cinv[ci], sh = csh[ci];
                if (active) {
                    if (tileInt) {
                        int t = tlo + tid;
#pragma unroll
                        for (int mm = 0; mm < M; ++mm) {
                            xl[mm * 256 + tid] = fmaf(xc[t], inv, sh);
                            t += d;
                        }
                    } else {
                        int t0 = tlo + tid;
#pragma unroll
                        for (int mm = 0; mm < M; ++mm) {
                            int t = t0 + mm * d;
                            float v = 0.f;
                            if ((unsigned)t < (unsigned)LL) v = fmaf(xc[t], inv, sh);
                            xl[mm * 256 + tid] = v;
                        }
                    }
                }
                __syncthreads();

                float wreg[LEN];
#pragma unroll
                for (int j = 0; j < LEN; ++j) wreg[j] = wsm[ci * LEN + j];
                float win[M];
#pragma unroll
                for (int mm = 0; mm < M; ++mm) win[mm] = xl[mm * 256 + tid];
#pragma unroll
                for (int j = 0; j < LEN; ++j)
#pragma unroll
                    for (int g = 0; g < GG; ++g)
                        acc[g] = fmaf(wreg[j], win[g + j], acc[g]);
            }

            if (active) {
#pragma unroll
                for (int g = 0; g < GG; ++g) {
                    int t = (qt + g) * d + rho;
                    if (t < Lout) {
                        float y = acc[g] + bias;
                        cnt += (y > 0.f) ? 1 : 0;
                        mx = fmaxf(mx, y);
                    }
                }
            }
        }
    }
    block_finish(cnt, mx, rm, rc, Lout, out, b, k);
}

__global__ __launch_bounds__(256) void conv_kernel(
    const float* __restrict__ x, const float* __restrict__ weights,
    const float* __restrict__ biases,
    const int* __restrict__ lengths, const int* __restrict__ dil,
    const int* __restrict__ pad, const int* __restrict__ ncis,
    const int* __restrict__ chidx,
    const float* __restrict__ wsf, const int* __restrict__ wbase,
    const int* __restrict__ cbase, float* __restrict__ out) {
    int k = blockIdx.x, b = blockIdx.y;
    __shared__ float xl[XLSZ];
    __shared__ float wsm[CC * 11];
    __shared__ int choff[CC];
    __shared__ float cinv[CC], csh[CC];
    __shared__ float rm[4];
    __shared__ int rc[4];

    int tid = threadIdx.x;
    int len = lengths[k], d = dil[k], p = pad[k], nci = ncis[k];
    int wb = wbase[k], cb = cbase[k];

    if (tid < nci) {
        int ch = chidx[cb + tid];
        choff[tid] = (b * CC + ch) * LL;
        cinv[tid] = wsf[b * CC + ch];
        csh[tid] = wsf[1280 + b * CC + ch];
    }
    int nw = nci * len;
    for (int i = tid; i < nw; i += 256) wsm[i] = weights[wb + i];
    __syncthreads();

    int span = (len - 1) * d;
    int Lout = LL + 2 * p - span;
    int ms = p / d;
    float bias = biases[k];
    int Qmax = (Lout + d - 1) / d;

    if (d <= 256) {
        switch (len) {
            case 7:  conv_S2<7>(x, xl, wsm, choff, cinv, csh, rm, rc, d, ms, Lout, nci, bias, out, b, k); break;
            case 9:  conv_S2<9>(x, xl, wsm, choff, cinv, csh, rm, rc, d, ms, Lout, nci, bias, out, b, k); break;
            default: conv_S2<11>(x, xl, wsm, choff, cinv, csh, rm, rc, d, ms, Lout, nci, bias, out, b, k); break;
        }
    } else if (Qmax > 12) {
        switch (len) {
            case 7:  conv_T2<7, 16>(x, xl, wsm, choff, cinv, csh, rm, rc, d, ms, Lout, nci, bias, out, b, k); break;
            case 9:  conv_T2<9, 16>(x, xl, wsm, choff, cinv, csh, rm, rc, d, ms, Lout, nci, bias, out, b, k); break;
            default: conv_T2<11, 16>(x, xl, wsm, choff, cinv, csh, rm, rc, d, ms, Lout, nci, bias, out, b, k); break;
        }
    } else {
        switch (len) {
            case 7:  conv_T2<7, 4>(x, xl, wsm, choff, cinv, csh, rm, rc, d, ms, Lout, nci, bias, out, b, k); break;
            case 9:  conv_T2<9, 4>(x, xl, wsm, choff, cinv, csh, rm, rc, d, ms, Lout, nci, bias, out, b, k); break;
            default: conv_T2<11, 4>(x, xl, wsm, choff, cinv, csh, rm, rc, d, ms, Lout, nci, bias, out, b, k); break;
        }
    }
}

extern "C" void kernel_launch(void* const* d_in, const int* in_sizes, int n_in,
                              void* d_out, int out_size, void* d_ws, size_t ws_size,
                              hipStream_t stream) {
    const float* x = (const float*)d_in[0];
    const float* weights = (const float*)d_in[1];
    const float* biases = (const float*)d_in[2];
    const int* lengths = (const int*)d_in[3];
    const int* dil = (const int*)d_in[4];
    const int* pad = (const int*)d_in[5];
    const int* ncis = (const int*)d_in[6];
    const int* chidx = (const int*)d_in[7];
    float* out = (float*)d_out;

    float* wsf = (float*)d_ws;
    int* wbase = (int*)((char*)d_ws + 2560 * sizeof(float));
    int* cbase = wbase + NK;

    stats_kernel<<<dim3(BB * CC), dim3(256), 0, stream>>>(x, wsf);
    prefix_kernel<<<dim3(1), dim3(256), 0, stream>>>(lengths, ncis, wbase, cbase);
    dim3 grid(NK, BB);
    conv_kernel<<<grid, dim3(256), 0, stream>>>(x, weights, biases, lengths, dil,
                                                pad, ncis, chidx, wsf, wbase,
                                                cbase, out);
}

// Round 7
// 3436.321 us; speedup vs baseline: 2.3538x; 1.3116x over previous
//
#include <hip/hip_runtime.h>

#define NK 256
#define BB 128
#define CC 10
#define LL 16384
#define EPSV 1e-10f
#define G 16
#define XLSZ 7424
#define MAXIT 26
#define WROW 12

__device__ __forceinline__ int gidx(int a) { return a + (a >> 5); }

__device__ __forceinline__ void block_finish(int cnt, float mx,
                                             float* rm, int* rc,
                                             int Lout, float* out, int b, int k) {
    int tid = threadIdx.x;
    for (int off = 32; off; off >>= 1) {
        mx = fmaxf(mx, __shfl_down(mx, off));
        cnt += __shfl_down(cnt, off);
    }
    int wv = tid >> 6, ln = tid & 63;
    if (ln == 0) { rm[wv] = mx; rc[wv] = cnt; }
    __syncthreads();
    if (tid == 0) {
#pragma unroll
        for (int i = 1; i < 4; ++i) { mx = fmaxf(mx, rm[i]); cnt += rc[i]; }
        size_t o = (size_t)b * (2 * NK) + 2 * k;
        out[o] = (float)cnt / (float)Lout;
        out[o + 1] = mx;
    }
}

__global__ __launch_bounds__(256) void stats_kernel(const float* __restrict__ x,
                                                    float* __restrict__ wsf) {
    int row = blockIdx.x;
    const float4* x4 = (const float4*)(x + (size_t)row * LL);
    int tid = threadIdx.x;
    float s = 0.f, s2 = 0.f;
    for (int i = tid; i < LL / 4; i += 256) {
        float4 v = x4[i];
        s += v.x + v.y + v.z + v.w;
        s2 += v.x * v.x + v.y * v.y + v.z * v.z + v.w * v.w;
    }
    for (int off = 32; off; off >>= 1) {
        s += __shfl_down(s, off);
        s2 += __shfl_down(s2, off);
    }
    __shared__ float as_[4], as2_[4];
    int wv = tid >> 6, ln = tid & 63;
    if (ln == 0) { as_[wv] = s; as2_[wv] = s2; }
    __syncthreads();
    if (tid == 0) {
        float S = as_[0] + as_[1] + as_[2] + as_[3];
        float S2 = as2_[0] + as2_[1] + as2_[2] + as2_[3];
        float mean = S / (float)LL;
        float var = (S2 - (float)LL * mean * mean) / (float)(LL - 1);
        var = fmaxf(var, 0.f);
        float inv = 1.f / (sqrtf(var) + EPSV);
        wsf[row] = inv;
        wsf[1280 + row] = -mean * inv;
    }
}

__global__ __launch_bounds__(256) void prefix_kernel(const int* __restrict__ lengths,
                                                     const int* __restrict__ ncis,
                                                     int* __restrict__ wbase,
                                                     int* __restrict__ cbase) {
    __shared__ int s1[NK], s2[NK];
    int k = threadIdx.x;
    int v1 = lengths[k] * ncis[k];
    int v2 = ncis[k];
    s1[k] = v1; s2[k] = v2;
    for (int off = 1; off < NK; off <<= 1) {
        __syncthreads();
        int a = (k >= off) ? s1[k - off] : 0;
        int b = (k >= off) ? s2[k - off] : 0;
        __syncthreads();
        s1[k] += a; s2[k] += b;
    }
    __syncthreads();
    wbase[k] = s1[k] - v1;
    cbase[k] = s2[k] - v2;
}

// ======== S2: d <= 256 — linear-t LDS tile, reg-prefetch staging ========
template <int LEN>
__device__ __forceinline__ void conv_S2(
    const float* __restrict__ x, float* __restrict__ xl,
    const float* __restrict__ wsm, const int* __restrict__ choff,
    const float* __restrict__ cinv, const float* __restrict__ csh,
    float* rm, int* rc, int d, int ms, int Lout, int nci, float bias,
    float* __restrict__ out, int b, int k) {
    constexpr int W = G + LEN - 1;
    const int tid = threadIdx.x;
    int cnt = 0;
    float mx = -3.4e38f;
    float negb = -bias;

    int qpt = 256 / d;
    int MT = qpt * G;
    int stot = d * (MT + LEN - 1);
    int Qmax = (Lout + d - 1) / d;
    int qi = tid / d;
    int rho = tid - qi * d;
    bool active = qi < qpt;
    int a0 = active ? (qi * G * d + rho) : 0;
    int sl0 = gidx(tid);

    float r[MAXIT];

    // ---- prefetch: raw x values for staged range [tb_, tb_+stot) ----
    auto prefetch = [&](const float* __restrict__ xc, int tb_) {
        int t0 = tb_ + tid;
        if (tb_ >= 0 && tb_ + stot <= LL) {
#pragma unroll
            for (int it = 0; it < MAXIT; ++it) {
                if (tid + (it << 8) < stot) r[it] = xc[t0 + (it << 8)];
            }
        } else {
#pragma unroll
            for (int it = 0; it < MAXIT; ++it) {
                if (tid + (it << 8) < stot) {
                    int t = t0 + (it << 8);
                    t = t < 0 ? 0 : (t > LL - 1 ? LL - 1 : t);
                    r[it] = xc[t];
                }
            }
        }
    };
    // ---- write: regs -> LDS with normalize + zero-fill ----
    auto writeStage = [&](int tb_, float inv, float sh) {
        int sl = sl0;
        if (tb_ >= 0 && tb_ + stot <= LL) {
#pragma unroll
            for (int it = 0; it < MAXIT; ++it) {
                if (tid + (it << 8) < stot) xl[sl] = fmaf(r[it], inv, sh);
                sl += 264;
            }
        } else {
            int t0 = tb_ + tid;
#pragma unroll
            for (int it = 0; it < MAXIT; ++it) {
                if (tid + (it << 8) < stot) {
                    int t = t0 + (it << 8);
                    float v = 0.f;
                    if ((unsigned)t < (unsigned)LL) v = fmaf(r[it], inv, sh);
                    xl[sl] = v;
                }
                sl += 264;
            }
        }
    };

    int tb = -ms * d;
    prefetch(x + choff[0], tb);

    for (int qt = 0; qt < Qmax; qt += MT) {
        float acc[G];
#pragma unroll
        for (int g = 0; g < G; ++g) acc[g] = 0.f;

        for (int ci = 0; ci < nci; ++ci) {
            __syncthreads();
            writeStage(tb, cinv[ci], csh[ci]);
            __syncthreads();

            // prefetch next channel-tile
            int nc = ci + 1, ntb = tb;
            bool has = true;
            if (nc == nci) { nc = 0; ntb = tb + MT * d; has = (qt + MT) < Qmax; }
            if (has) prefetch(x + choff[nc], ntb);

            // compute
            float wreg[WROW];
            const float4* wv4 = (const float4*)&wsm[ci * WROW];
#pragma unroll
            for (int u = 0; u < (LEN + 3) / 4; ++u) {
                float4 w4 = wv4[u];
                wreg[4 * u + 0] = w4.x; wreg[4 * u + 1] = w4.y;
                wreg[4 * u + 2] = w4.z; wreg[4 * u + 3] = w4.w;
            }
            float win[W];
            int a = a0;
#pragma unroll
            for (int i = 0; i < W; ++i) {
                win[i] = xl[gidx(a)];
                a += d;
            }
#pragma unroll
            for (int j = 0; j < LEN; ++j)
#pragma unroll
                for (int g = 0; g < G; ++g)
                    acc[g] = fmaf(wreg[j], win[g + j], acc[g]);
        }

        if (active) {
            int qb = qt + qi * G;
            if ((qb + G) * d <= Lout) {
                float am = acc[0];
#pragma unroll
                for (int g = 1; g < G; ++g) am = fmaxf(am, acc[g]);
                mx = fmaxf(mx, am + bias);
#pragma unroll
                for (int g = 0; g < G; ++g) cnt += (acc[g] > negb) ? 1 : 0;
            } else {
#pragma unroll
                for (int g = 0; g < G; ++g) {
                    int t = (qb + g) * d + rho;
                    if (t < Lout) {
                        float y = acc[g] + bias;
                        cnt += (y > 0.f) ? 1 : 0;
                        mx = fmaxf(mx, y);
                    }
                }
            }
        }
        tb += MT * d;
    }
    block_finish(cnt, mx, rm, rc, Lout, out, b, k);
}

// ======== T2: d > 256 — rho-blocked [M][256] LDS, reg-prefetch staging ======
template <int LEN, int GG>
__device__ __forceinline__ void conv_T2(
    const float* __restrict__ x, float* __restrict__ xl,
    const float* __restrict__ wsm, const int* __restrict__ choff,
    const float* __restrict__ cinv, const float* __restrict__ csh,
    float* rm, int* rc, int d, int ms, int Lout, int nci, float bias,
    float* __restrict__ out, int b, int k) {
    constexpr int M = GG + LEN - 1;
    const int tid = threadIdx.x;
    int cnt = 0;
    float mx = -3.4e38f;
    int Qmax = (Lout + d - 1) / d;
    int tlo0 = -ms * d;

    float r[M];

    auto prefetch = [&](const float* __restrict__ xc, int tlo_) {
        int t = tlo_ + tid;
        if (tlo_ >= 0 && tlo_ + 255 + (M - 1) * d < LL) {
#pragma unroll
            for (int mm = 0; mm < M; ++mm) { r[mm] = xc[t]; t += d; }
        } else {
#pragma unroll
            for (int mm = 0; mm < M; ++mm) {
                int tc = t < 0 ? 0 : (t > LL - 1 ? LL - 1 : t);
                r[mm] = xc[tc];
                t += d;
            }
        }
    };
    auto writeStage = [&](int tlo_, float inv, float sh) {
        if (tlo_ >= 0 && tlo_ + 255 + (M - 1) * d < LL) {
#pragma unroll
            for (int mm = 0; mm < M; ++mm) xl[mm * 256 + tid] = fmaf(r[mm], inv, sh);
        } else {
            int t = tlo_ + tid;
#pragma unroll
            for (int mm = 0; mm < M; ++mm) {
                float v = 0.f;
                if ((unsigned)t < (unsigned)LL) v = fmaf(r[mm], inv, sh);
                xl[mm * 256 + tid] = v;
                t += d;
            }
        }
    };

    prefetch(x + choff[0], tlo0);

    for (int r0 = 0; r0 < d; r0 += 256) {
        int rho = r0 + tid;
        bool active = rho < d;
        int tlo = tlo0 + r0;
        for (int qt = 0; qt < Qmax; qt += GG) {
            float acc[GG];
#pragma unroll
            for (int g = 0; g < GG; ++g) acc[g] = 0.f;

            for (int ci = 0; ci < nci; ++ci) {
                __syncthreads();
                writeStage(tlo, cinv[ci], csh[ci]);
                __syncthreads();

                int nc = ci + 1, ntlo = tlo;
                bool has = true;
                if (nc == nci) {
                    nc = 0;
                    if (qt + GG < Qmax) ntlo = tlo + GG * d;
                    else if (r0 + 256 < d) ntlo = tlo0 + r0 + 256;
                    else has = false;
                }
                if (has) prefetch(x + choff[nc], ntlo);

                float wreg[WROW];
                const float4* wv4 = (const float4*)&wsm[ci * WROW];
#pragma unroll
                for (int u = 0; u < (LEN + 3) / 4; ++u) {
                    float4 w4 = wv4[u];
                    wreg[4 * u + 0] = w4.x; wreg[4 * u + 1] = w4.y;
                    wreg[4 * u + 2] = w4.z; wreg[4 * u + 3] = w4.w;
                }
                float win[M];
#pragma unroll
                for (int mm = 0; mm < M; ++mm) win[mm] = xl[mm * 256 + tid];
#pragma unroll
                for (int j = 0; j < LEN; ++j)
#pragma unroll
                    for (int g = 0; g < GG; ++g)
                        acc[g] = fmaf(wreg[j], win[g + j], acc[g]);
            }

            if (active) {
#pragma unroll
                for (int g = 0; g < GG; ++g) {
                    int t = (qt + g) * d + rho;
                    if (t < Lout) {
                        float y = acc[g] + bias;
                        cnt += (y > 0.f) ? 1 : 0;
                        mx = fmaxf(mx, y);
                    }
                }
            }
            tlo += GG * d;
        }
    }
    block_finish(cnt, mx, rm, rc, Lout, out, b, k);
}

__global__ __launch_bounds__(256) void conv_kernel(
    const float* __restrict__ x, const float* __restrict__ weights,
    const float* __restrict__ biases,
    const int* __restrict__ lengths, const int* __restrict__ dil,
    const int* __restrict__ pad, const int* __restrict__ ncis,
    const int* __restrict__ chidx,
    const float* __restrict__ wsf, const int* __restrict__ wbase,
    const int* __restrict__ cbase, float* __restrict__ out) {
    int k = blockIdx.x, b = blockIdx.y;
    __shared__ __align__(16) float xl[XLSZ];
    __shared__ __align__(16) float wsm[CC * WROW];
    __shared__ int choff[CC];
    __shared__ float cinv[CC], csh[CC];
    __shared__ float rm[4];
    __shared__ int rc[4];

    int tid = threadIdx.x;
    int len = lengths[k], d = dil[k], p = pad[k], nci = ncis[k];
    int wb = wbase[k], cb = cbase[k];

    if (tid < nci) {
        int ch = chidx[cb + tid];
        choff[tid] = (b * CC + ch) * LL;
        cinv[tid] = wsf[b * CC + ch];
        csh[tid] = wsf[1280 + b * CC + ch];
    }
    for (int i = tid; i < nci * WROW; i += 256) {
        int ci = i / WROW, j = i - ci * WROW;
        wsm[i] = (j < len) ? weights[wb + ci * len + j] : 0.f;
    }
    __syncthreads();

    int span = (len - 1) * d;
    int Lout = LL + 2 * p - span;
    int ms = p / d;
    float bias = biases[k];
    int Qmax = (Lout + d - 1) / d;

    if (d <= 256) {
        switch (len) {
            case 7:  conv_S2<7>(x, xl, wsm, choff, cinv, csh, rm, rc, d, ms, Lout, nci, bias, out, b, k); break;
            case 9:  conv_S2<9>(x, xl, wsm, choff, cinv, csh, rm, rc, d, ms, Lout, nci, bias, out, b, k); break;
            default: conv_S2<11>(x, xl, wsm, choff, cinv, csh, rm, rc, d, ms, Lout, nci, bias, out, b, k); break;
        }
    } else if (Qmax > 12) {
        switch (len) {
            case 7:  conv_T2<7, 16>(x, xl, wsm, choff, cinv, csh, rm, rc, d, ms, Lout, nci, bias, out, b, k); break;
            case 9:  conv_T2<9, 16>(x, xl, wsm, choff, cinv, csh, rm, rc, d, ms, Lout, nci, bias, out, b, k); break;
            default: conv_T2<11, 16>(x, xl, wsm, choff, cinv, csh, rm, rc, d, ms, Lout, nci, bias, out, b, k); break;
        }
    } else {
        switch (len) {
            case 7:  conv_T2<7, 4>(x, xl, wsm, choff, cinv, csh, rm, rc, d, ms, Lout, nci, bias, out, b, k); break;
            case 9:  conv_T2<9, 4>(x, xl, wsm, choff, cinv, csh, rm, rc, d, ms, Lout, nci, bias, out, b, k); break;
            default: conv_T2<11, 4>(x, xl, wsm, choff, cinv, csh, rm, rc, d, ms, Lout, nci, bias, out, b, k); break;
        }
    }
}

extern "C" void kernel_launch(void* const* d_in, const int* in_sizes, int n_in,
                              void* d_out, int out_size, void* d_ws, size_t ws_size,
                              hipStream_t stream) {
    const float* x = (const float*)d_in[0];
    const float* weights = (const float*)d_in[1];
    const float* biases = (const float*)d_in[2];
    const int* lengths = (const int*)d_in[3];
    const int* dil = (const int*)d_in[4];
    const int* pad = (const int*)d_in[5];
    const int* ncis = (const int*)d_in[6];
    const int* chidx = (const int*)d_in[7];
    float* out = (float*)d_out;

    float* wsf = (float*)d_ws;
    int* wbase = (int*)((char*)d_ws + 2560 * sizeof(float));
    int* cbase = wbase + NK;

    stats_kernel<<<dim3(BB * CC), dim3(256), 0, stream>>>(x, wsf);
    prefix_kernel<<<dim3(1), dim3(256), 0, stream>>>(lengths, ncis, wbase, cbase);
    dim3 grid(NK, BB);
    conv_kernel<<<grid, dim3(256), 0, stream>>>(x, weights, biases, lengths, dil,
                                                pad, ncis, chidx, wsf, wbase,
                                                cbase, out);
}